// Round 5
// baseline (9776.196 us; speedup 1.0000x reference)
//
#include <hip/hip_runtime.h>
#include <hip/hip_bf16.h>
#include <stdint.h>

#define TT 1024
#define BB 32
#define DD 1024

typedef __attribute__((ext_vector_type(8))) short short8;
typedef __attribute__((ext_vector_type(4))) unsigned short ushort4v;
typedef __attribute__((ext_vector_type(4))) float floatx4;
typedef __attribute__((ext_vector_type(2))) unsigned long long ull2;

static __device__ __forceinline__ unsigned short f2bf(float f){
  unsigned u = __float_as_uint(f);
  u += 0x7fffu + ((u >> 16) & 1u);   // RNE
  return (unsigned short)(u >> 16);
}
static __device__ __forceinline__ float bf2f(unsigned short s){
  return __uint_as_float(((unsigned)s) << 16);
}
static __device__ __forceinline__ float sigm(float x){
  return __fdividef(1.0f, 1.0f + __expf(-x));
}
static __device__ __forceinline__ float fast_tanh(float x){
  float e = __expf(2.0f * x);
  return 1.0f - __fdividef(2.0f, e + 1.0f);
}

// ---------------- workspace layout (bytes) ----------------
// frag: [t][bh(2)][nt(128)][lane(64)][4] bf16; nt 0..63 alpha preact, 64..127 wx.
// h HISTORY (for out_writer) goes into the dead alpha halves via PLAIN stores
// (L2-resident from the alpha reads -> fast ack, lazy writeback, off critical path).
// h EXCHANGE goes through a fixed, permanently-MALL-hot 2x64KB double buffer,
// written/read ONLY with relaxed agent-scope (L2-bypassing) atomics.
#define WS_FRAG_BYTES (134217728ull)                 // 1024*2*128*64*4*2
#define WS_WCAT_OFF   (WS_FRAG_BYTES)
#define WS_WCAT_BYTES (4194304ull)                   // 2048*1024*2 bf16 [Walpha;Wx]
#define WS_H1_OFF     (WS_WCAT_OFF + WS_WCAT_BYTES)  // 32*1024 bf16 h1 history
#define WS_HBUF_OFF   (WS_H1_OFF + 65536ull)         // 2 * 32*1024 bf16 exchange
#define WS_FLAG_OFF   (WS_HBUF_OFF + 131072ull)      // 128 flags, 128B apart

// ---------------- init: cast weights, seed exchange buf 0 with h0, write hout[0], zero flags
__global__ void init_kernel(const float* __restrict__ Wa, const float* __restrict__ Wx,
                            const float* __restrict__ h0, float* __restrict__ hout0,
                            unsigned short* __restrict__ Wcat,
                            unsigned short* __restrict__ hbuf,
                            unsigned* __restrict__ flags)
{
  long i = (long)blockIdx.x * 256 + threadIdx.x;
  if (blockIdx.x == 0 && threadIdx.x < 128)
    __hip_atomic_store(&flags[threadIdx.x * 32], 0u, __ATOMIC_RELAXED, __HIP_MEMORY_SCOPE_AGENT);
  const long NW = 2048L * 1024L;
  for (long idx = i; idx < NW; idx += (long)gridDim.x * 256L){
    long r = idx >> 10, c = idx & 1023;
    float v = (r < 1024) ? Wa[r*1024 + c] : Wx[(r-1024)*1024 + c];
    Wcat[idx] = f2bf(v);
  }
  const long NH = 32L * 1024L;
  for (long idx = i; idx < NH; idx += (long)gridDim.x * 256L){
    float v = h0[idx];
    hbuf[idx] = f2bf(v);     // exchange buffer 0 = h0
    hout0[idx] = v;          // hout[0] = h0 (fp32)
  }
}

// ---------------- precompute GEMM: [alpha_preact | wx] for all (t,b), bf16 MFMA-fragment layout
__global__ __launch_bounds__(256) void pre_gemm(
    const float* __restrict__ x, const unsigned short* __restrict__ Wcat,
    const float* __restrict__ b_alpha, const float* __restrict__ b_x,
    unsigned short* __restrict__ frag)
{
  __shared__ unsigned short A_lds[128*72];
  __shared__ unsigned short B_lds[128*72];
  const int tid = threadIdx.x;
  const int lane = tid & 63;
  const int w = tid >> 6;
  const int wm = w >> 1, wn = w & 1;
  const long m0 = (long)blockIdx.y * 128;
  const int n0 = blockIdx.x * 128;

  floatx4 acc[4][4];
#pragma unroll
  for (int i=0;i<4;++i)
#pragma unroll
    for (int j=0;j<4;++j) acc[i][j] = (floatx4){0.f,0.f,0.f,0.f};

  for (int kt=0; kt<16; ++kt){
    const int k0 = kt*64;
    __syncthreads();
#pragma unroll
    for (int rep=0; rep<4; ++rep){
      int flat = rep*2048 + tid*8;
      int r = flat >> 6, c = flat & 63;
      const float* src = &x[(m0 + r)*1024 + k0 + c];
      floatx4 f0 = *(const floatx4*)src;
      floatx4 f1 = *(const floatx4*)(src + 4);
      short8 v;
      v[0]=(short)f2bf(f0[0]); v[1]=(short)f2bf(f0[1]); v[2]=(short)f2bf(f0[2]); v[3]=(short)f2bf(f0[3]);
      v[4]=(short)f2bf(f1[0]); v[5]=(short)f2bf(f1[1]); v[6]=(short)f2bf(f1[2]); v[7]=(short)f2bf(f1[3]);
      *(short8*)&A_lds[r*72 + c] = v;
      short8 bv = *(const short8*)&Wcat[(long)(n0 + r)*1024 + k0 + c];
      *(short8*)&B_lds[r*72 + c] = bv;
    }
    __syncthreads();
#pragma unroll
    for (int kb=0; kb<2; ++kb){
      short8 a[4], b[4];
#pragma unroll
      for (int f=0; f<4; ++f)
        a[f] = *(const short8*)&A_lds[(wm*64 + f*16 + (lane&15))*72 + kb*32 + (lane>>4)*8];
#pragma unroll
      for (int f=0; f<4; ++f)
        b[f] = *(const short8*)&B_lds[(wn*64 + f*16 + (lane&15))*72 + kb*32 + (lane>>4)*8];
#pragma unroll
      for (int fm=0; fm<4; ++fm)
#pragma unroll
        for (int fn=0; fn<4; ++fn)
          acc[fm][fn] = __builtin_amdgcn_mfma_f32_16x16x32_bf16(a[fm], b[fn], acc[fm][fn], 0, 0, 0);
    }
  }

#pragma unroll
  for (int fm=0; fm<4; ++fm){
    const long mrow = m0 + wm*64 + fm*16;
    const int t  = (int)(mrow >> 5);
    const int bh = (int)((mrow >> 4) & 1);
#pragma unroll
    for (int fn=0; fn<4; ++fn){
      const int nf  = n0 + wn*64 + fn*16;
      const int nt  = nf >> 4;
      const int col = nf + (lane & 15);
      floatx4 v = acc[fm][fn];
      const float bias = (col < DD) ? b_alpha[col] : b_x[col - DD];
      ushort4v o;
#pragma unroll
      for (int i=0;i<4;++i) o[i] = f2bf(v[i] + bias);
      *(ushort4v*)&frag[((((long)t*2 + bh)*128 + nt)*64 + lane)*4] = o;
    }
  }
}

// ---------------- sequential scan (32 wgs = 2 groups x 16 slices)
// Exchange: fixed hot double buffer, relaxed agent atomics both sides (MALL is the
// single coherence point; buffer lines never enter any L2 so can't go stale).
// 2-buffer safety: flag>=t+1 from a wg implies its step-t reads of hbuf[t&1]
// completed (reads precede stores+vmcnt-drain+flag in program order).
__global__ __launch_bounds__(256, 1) void scan_kernel(
    const float* __restrict__ Wh, const float* __restrict__ h0,
    unsigned short* frag,                  // history storage (dead alpha halves)
    unsigned short* hbuf,                  // 2 x [32][1024] bf16 exchange
    unsigned short* h1buf,                 // history for t=1
    unsigned* flags)
{
  __shared__ unsigned short W_lds[64*1024];  // XOR-swizzled, stride 1024
  __shared__ unsigned short tile[16*72];     // per-step h staging (16 rows x 64 cols + pad)
  const int tid  = threadIdx.x;
  const int lane = tid & 63;
  const int w    = tid >> 6;
  const int bh   = blockIdx.x & 1;
  const int wsld = blockIdx.x >> 1;     // 0..15 weight slice
  const int base_r = wsld * 64;

  // one-time: W_h slice fp32 -> bf16 LDS, 16B-granule XOR swizzle:
  // element (r,c) stored at r*1024 + (c ^ ((r&7)*8))  [shorts]
  for (int it=0; it<64; ++it){
    const int r = it, c = tid*4;
    floatx4 f = *(const floatx4*)&Wh[(long)(base_r + r)*1024 + c];
    ushort4v v;
    v[0]=f2bf(f[0]); v[1]=f2bf(f[1]); v[2]=f2bf(f[2]); v[3]=f2bf(f[3]);
    *(ushort4v*)&W_lds[r*1024 + (c ^ ((r&7)*8))] = v;
  }

  const int n0   = base_r + w*16;
  const int colf = n0 + (lane & 15);
  const int nt_a = n0 >> 4;
  float hp[4];
#pragma unroll
  for (int i=0;i<4;++i){
    int gb = bh*16 + (lane>>4)*4 + i;
    hp[i] = h0[(long)gb*1024 + colf];
  }
  __syncthreads();

  // per-WAVE flags: flag index = bh*64 + wsld*4 + w, stride 32 uints (128B)
  unsigned* myflag   = flags + (bh*64 + wsld*4 + w)*32;
  unsigned* grpflags = flags + bh*64*32;
  const int hrow = lane & 15;
  const int g8   = (lane >> 4) * 8;
  const int brow = w*16 + (lane & 15);
  const int boff0 = g8 ^ ((brow & 7) * 8);
  const unsigned short* Wrow = &W_lds[brow * 1024];

  // preload frag for t=0 (plain loads)
  long fb = (((long)0*2 + bh)*128 + nt_a)*64 + lane;
  ushort4v al = *(const ushort4v*)&frag[fb*4];
  ushort4v wx = *(const ushort4v*)&frag[(fb + 64*64)*4];

  const int hb4 = (hrow*1024 + g8) >> 2;   // per-lane base, ull units

  for (int t=0; t<TT; ++t){
    if (t > 0){
      const unsigned tgt = (unsigned)t;
      if (w == 0){
        for (;;){
          unsigned v = __hip_atomic_load(&grpflags[lane*32],
                                         __ATOMIC_RELAXED, __HIP_MEMORY_SCOPE_AGENT);
          if (__all(v >= tgt)) break;
        }
      }
      __syncthreads();                  // release waves 1..3 after flags observed
      asm volatile("" ::: "memory");
    }

    // h GEMM: A from hot exchange buffer via L2-bypassing atomic 8B loads
    const unsigned long long* hsrc64 =
        (const unsigned long long*)(hbuf + (t & 1)*32768 + bh*16384);

    floatx4 ac0 = (floatx4){0.f,0.f,0.f,0.f}, ac1 = ac0, ac2 = ac0, ac3 = ac0;
#pragma unroll
    for (int kb=0; kb<32; kb+=4){
#pragma unroll
      for (int j=0;j<4;++j){
        unsigned long long q0 = __hip_atomic_load(&hsrc64[hb4 + (kb+j)*8],
                                  __ATOMIC_RELAXED, __HIP_MEMORY_SCOPE_AGENT);
        unsigned long long q1 = __hip_atomic_load(&hsrc64[hb4 + (kb+j)*8 + 1],
                                  __ATOMIC_RELAXED, __HIP_MEMORY_SCOPE_AGENT);
        ull2 q; q.x = q0; q.y = q1;
        short8 afr = __builtin_bit_cast(short8, q);
        short8 bfr = *(const short8*)&Wrow[((kb+j)*32) ^ boff0];
        if (j==0) ac0 = __builtin_amdgcn_mfma_f32_16x16x32_bf16(afr, bfr, ac0, 0, 0, 0);
        if (j==1) ac1 = __builtin_amdgcn_mfma_f32_16x16x32_bf16(afr, bfr, ac1, 0, 0, 0);
        if (j==2) ac2 = __builtin_amdgcn_mfma_f32_16x16x32_bf16(afr, bfr, ac2, 0, 0, 0);
        if (j==3) ac3 = __builtin_amdgcn_mfma_f32_16x16x32_bf16(afr, bfr, ac3, 0, 0, 0);
      }
    }
    floatx4 acc = (ac0 + ac1) + (ac2 + ac3);

    // epilogue -> LDS tile (rows=batch-in-group, cols=wg-local feature)
#pragma unroll
    for (int i=0;i<4;++i){
      float s  = acc[i] + bf2f(wx[i]);
      float v  = fast_tanh(s);
      float aa = sigm(bf2f(al[i]));
      float hn = aa*hp[i] + (1.0f - aa)*v;
      tile[((lane>>4)*4 + i)*72 + w*16 + (lane&15)] = f2bf(hn);
      hp[i] = hn;
    }
    __syncthreads();   // tile complete

    // prefetch next step's alpha/wx early (plain loads, deep in pipeline)
    if (t + 1 < TT){
      fb = (((long)(t+1)*2 + bh)*128 + nt_a)*64 + lane;
      al = *(const ushort4v*)&frag[fb*4];
      wx = *(const ushort4v*)&frag[(fb + 64*64)*4];
    }

    // stores: 16 consecutive tids cover 128B/row contiguous -> full-sector writes.
    // wave w handles rows w*4 .. w*4+3 (its own vmcnt covers them).
    {
      const int row  = tid >> 4;            // 0..15
      const int off  = (tid & 15) * 4;      // shorts
      unsigned long long v = *(const unsigned long long*)&tile[row*72 + off];
      // exchange: hot double buffer, atomic (L2-bypass, MALL-resident)
      unsigned short* hx = hbuf + ((t+1) & 1)*32768 + (bh*16 + row)*1024 + base_r + off;
      __hip_atomic_store((unsigned long long*)hx, v,
                         __ATOMIC_RELAXED, __HIP_MEMORY_SCOPE_AGENT);
      // history: plain store (L2-resident lines from alpha reads; lazy writeback)
      unsigned short* hh = (t == 0) ? (h1buf + bh*16384 + row*1024 + base_r + off)
                                    : (frag + ((long)(t-1)*2 + bh)*32768 + row*1024 + base_r + off);
      *(unsigned long long*)hh = v;
    }

    if (t + 1 < TT){
      asm volatile("s_waitcnt vmcnt(0)" ::: "memory");  // exchange stores acked at MALL
      if (lane == 0)
        __hip_atomic_store(myflag, (unsigned)(t + 1),
                           __ATOMIC_RELAXED, __HIP_MEMORY_SCOPE_AGENT);
    }
  }
}

// ---------------- expand bf16 h -> fp32 out/hout (memory-bound, off critical path)
__global__ __launch_bounds__(256) void out_writer(
    const unsigned short* __restrict__ frag,
    const unsigned short* __restrict__ h1buf,
    float* __restrict__ out, float* __restrict__ hout)
{
  const int t1 = blockIdx.z + 1;          // 1..1024
  const int bh = blockIdx.y;
  const int e  = (blockIdx.x*256 + threadIdx.x)*8;
  const int row = e >> 10, col = e & 1023;
  const unsigned short* src = (t1 == 1) ? (h1buf + bh*16384)
                                        : (frag + ((long)(t1-2)*2 + bh)*32768);
  short8 v = *(const short8*)&src[e];
  float o[8], hh[8];
#pragma unroll
  for (int j=0;j<8;++j){
    float h = bf2f((unsigned short)v[j]);
    float sg = sigm(h);
    hh[j] = h;
    o[j]  = h*h*sg;       // h * silu(h)
  }
  long ob = ((long)(t1-1)*BB + bh*16 + row)*DD + col;
  long hb = ((long)t1*BB + bh*16 + row)*DD + col;
  *(floatx4*)&out[ob]     = (floatx4){o[0],o[1],o[2],o[3]};
  *(floatx4*)&out[ob+4]   = (floatx4){o[4],o[5],o[6],o[7]};
  *(floatx4*)&hout[hb]    = (floatx4){hh[0],hh[1],hh[2],hh[3]};
  *(floatx4*)&hout[hb+4]  = (floatx4){hh[4],hh[5],hh[6],hh[7]};
}

extern "C" void kernel_launch(void* const* d_in, const int* in_sizes, int n_in,
                              void* d_out, int out_size, void* d_ws, size_t ws_size,
                              hipStream_t stream)
{
  const float* x  = (const float*)d_in[0];
  const float* h0 = (const float*)d_in[1];
  const float* Wa = (const float*)d_in[2];
  const float* ba = (const float*)d_in[3];
  const float* Wh = (const float*)d_in[4];
  const float* Wx = (const float*)d_in[5];
  const float* bx = (const float*)d_in[6];

  float* out  = (float*)d_out;                       // [T,B,D]
  float* hout = out + (long)TT*BB*DD;                // [T+1,B,D]

  uint8_t* ws = (uint8_t*)d_ws;
  unsigned short* frag  = (unsigned short*)(ws);
  unsigned short* Wcat  = (unsigned short*)(ws + WS_WCAT_OFF);
  unsigned short* h1buf = (unsigned short*)(ws + WS_H1_OFF);
  unsigned short* hbuf  = (unsigned short*)(ws + WS_HBUF_OFF);
  unsigned*       flags = (unsigned*)      (ws + WS_FLAG_OFF);

  init_kernel<<<8192, 256, 0, stream>>>(Wa, Wx, h0, hout, Wcat, hbuf, flags);
  pre_gemm<<<dim3(16, 256), 256, 0, stream>>>(x, Wcat, ba, bx, frag);
  scan_kernel<<<32, 256, 0, stream>>>(Wh, h0, frag, hbuf, h1buf, flags);
  out_writer<<<dim3(8, 2, 1024), 256, 0, stream>>>(frag, h1buf, out, hout);
}

// Round 6
// 6785.899 us; speedup vs baseline: 1.4407x; 1.4407x over previous
//
#include <hip/hip_runtime.h>
#include <hip/hip_bf16.h>
#include <stdint.h>

#define TT 1024
#define BB 32
#define DD 1024

typedef __attribute__((ext_vector_type(8))) short short8;
typedef __attribute__((ext_vector_type(4))) unsigned short ushort4v;
typedef __attribute__((ext_vector_type(4))) float floatx4;

static __device__ __forceinline__ unsigned short f2bf(float f){
  unsigned u = __float_as_uint(f);
  u += 0x7fffu + ((u >> 16) & 1u);   // RNE
  return (unsigned short)(u >> 16);
}
static __device__ __forceinline__ float bf2f(unsigned short s){
  return __uint_as_float(((unsigned)s) << 16);
}
static __device__ __forceinline__ float sigm(float x){
  return __fdividef(1.0f, 1.0f + __expf(-x));
}
static __device__ __forceinline__ float fast_tanh(float x){
  float e = __expf(2.0f * x);
  return 1.0f - __fdividef(2.0f, e + 1.0f);
}

// ---------------- workspace layout (bytes) ----------------
// frag: [t][bh(2)][nt(128)][lane(64)][4] bf16; nt 0..63 alpha preact, 64..127 wx.
// h_{t+1} (16 rows x 1024 cols per group) is stored full-sector via relaxed agent
// atomics into the DEAD alpha half of frag[t-1]; consumers plain-load it at step
// t+1 (virgin-L2: alpha halves are only ever read with atomic loads, wx lives in
// different cache lines, so no L1/L2 ever holds a stale copy).
#define WS_FRAG_BYTES (134217728ull)                 // 1024*2*128*64*4*2
#define WS_WCAT_OFF   (WS_FRAG_BYTES)
#define WS_WCAT_BYTES (4194304ull)                   // 2048*1024*2 bf16 [Walpha;Wx]
#define WS_HINIT_OFF  (WS_WCAT_OFF + WS_WCAT_BYTES)  // 32*1024 bf16 h0
#define WS_H1_OFF     (WS_HINIT_OFF + 65536ull)      // 32*1024 bf16 h1
#define WS_FLAG_OFF   (WS_H1_OFF + 65536ull)         // 128 flags, 128B apart

// ---------------- init
__global__ void init_kernel(const float* __restrict__ Wa, const float* __restrict__ Wx,
                            const float* __restrict__ h0, float* __restrict__ hout0,
                            unsigned short* __restrict__ Wcat,
                            unsigned short* __restrict__ hinit,
                            unsigned* __restrict__ flags)
{
  long i = (long)blockIdx.x * 256 + threadIdx.x;
  if (blockIdx.x == 0 && threadIdx.x < 128)
    __hip_atomic_store(&flags[threadIdx.x * 32], 0u, __ATOMIC_RELAXED, __HIP_MEMORY_SCOPE_AGENT);
  const long NW = 2048L * 1024L;
  for (long idx = i; idx < NW; idx += (long)gridDim.x * 256L){
    long r = idx >> 10, c = idx & 1023;
    float v = (r < 1024) ? Wa[r*1024 + c] : Wx[(r-1024)*1024 + c];
    Wcat[idx] = f2bf(v);
  }
  const long NH = 32L * 1024L;
  for (long idx = i; idx < NH; idx += (long)gridDim.x * 256L){
    float v = h0[idx];
    hinit[idx] = f2bf(v);
    hout0[idx] = v;          // hout[0] = h0 (fp32)
  }
}

// ---------------- precompute GEMM (unchanged)
__global__ __launch_bounds__(256) void pre_gemm(
    const float* __restrict__ x, const unsigned short* __restrict__ Wcat,
    const float* __restrict__ b_alpha, const float* __restrict__ b_x,
    unsigned short* __restrict__ frag)
{
  __shared__ unsigned short A_lds[128*72];
  __shared__ unsigned short B_lds[128*72];
  const int tid = threadIdx.x;
  const int lane = tid & 63;
  const int w = tid >> 6;
  const int wm = w >> 1, wn = w & 1;
  const long m0 = (long)blockIdx.y * 128;
  const int n0 = blockIdx.x * 128;

  floatx4 acc[4][4];
#pragma unroll
  for (int i=0;i<4;++i)
#pragma unroll
    for (int j=0;j<4;++j) acc[i][j] = (floatx4){0.f,0.f,0.f,0.f};

  for (int kt=0; kt<16; ++kt){
    const int k0 = kt*64;
    __syncthreads();
#pragma unroll
    for (int rep=0; rep<4; ++rep){
      int flat = rep*2048 + tid*8;
      int r = flat >> 6, c = flat & 63;
      const float* src = &x[(m0 + r)*1024 + k0 + c];
      floatx4 f0 = *(const floatx4*)src;
      floatx4 f1 = *(const floatx4*)(src + 4);
      short8 v;
      v[0]=(short)f2bf(f0[0]); v[1]=(short)f2bf(f0[1]); v[2]=(short)f2bf(f0[2]); v[3]=(short)f2bf(f0[3]);
      v[4]=(short)f2bf(f1[0]); v[5]=(short)f2bf(f1[1]); v[6]=(short)f2bf(f1[2]); v[7]=(short)f2bf(f1[3]);
      *(short8*)&A_lds[r*72 + c] = v;
      short8 bv = *(const short8*)&Wcat[(long)(n0 + r)*1024 + k0 + c];
      *(short8*)&B_lds[r*72 + c] = bv;
    }
    __syncthreads();
#pragma unroll
    for (int kb=0; kb<2; ++kb){
      short8 a[4], b[4];
#pragma unroll
      for (int f=0; f<4; ++f)
        a[f] = *(const short8*)&A_lds[(wm*64 + f*16 + (lane&15))*72 + kb*32 + (lane>>4)*8];
#pragma unroll
      for (int f=0; f<4; ++f)
        b[f] = *(const short8*)&B_lds[(wn*64 + f*16 + (lane&15))*72 + kb*32 + (lane>>4)*8];
#pragma unroll
      for (int fm=0; fm<4; ++fm)
#pragma unroll
        for (int fn=0; fn<4; ++fn)
          acc[fm][fn] = __builtin_amdgcn_mfma_f32_16x16x32_bf16(a[fm], b[fn], acc[fm][fn], 0, 0, 0);
    }
  }

#pragma unroll
  for (int fm=0; fm<4; ++fm){
    const long mrow = m0 + wm*64 + fm*16;
    const int t  = (int)(mrow >> 5);
    const int bh = (int)((mrow >> 4) & 1);
#pragma unroll
    for (int fn=0; fn<4; ++fn){
      const int nf  = n0 + wn*64 + fn*16;
      const int nt  = nf >> 4;
      const int col = nf + (lane & 15);
      floatx4 v = acc[fm][fn];
      const float bias = (col < DD) ? b_alpha[col] : b_x[col - DD];
      ushort4v o;
#pragma unroll
      for (int i=0;i<4;++i) o[i] = f2bf(v[i] + bias);
      *(ushort4v*)&frag[((((long)t*2 + bh)*128 + nt)*64 + lane)*4] = o;
    }
  }
}

// ---------------- sequential scan: chunked producer-consumer pipeline
// 32 wgs = 2 groups x 16 slices. wg s owns output cols [64s,64s+64) AND produces
// h-chunk s. Per step, consumers process K-chunks in ring order starting at own
// chunk (from LDS tile, no wait); remote chunk j is gated by a 64-lane flag
// monitor (lane L watches flag L: chunk L>>2, wave L&3) with one ballot -> ready
// mask. Flags are per-wave, set after vmcnt-counted store drain.
#define TILE_SZ (16*72)
__global__ __launch_bounds__(256, 1) void scan_kernel(
    const float* __restrict__ Wh, const float* __restrict__ h0,
    unsigned short* frag,
    const unsigned short* __restrict__ hinit,
    unsigned short* h1buf,
    unsigned* flags)
{
  __shared__ unsigned short W_lds[64*1024];     // XOR-swizzled, 128 KB
  __shared__ unsigned short tile2[2*TILE_SZ];   // ping-pong own-chunk staging
  const int tid  = threadIdx.x;
  const int lane = tid & 63;
  const int w    = tid >> 6;
  const int bh   = blockIdx.x & 1;
  const int s    = blockIdx.x >> 1;     // 0..15 slice / chunk id
  const int base_r = s * 64;

  // W_h slice fp32 -> bf16 LDS, 16B-granule XOR swizzle: (r,c) at r*1024 + (c ^ ((r&7)*8))
  for (int it=0; it<64; ++it){
    const int r = it, c = tid*4;
    floatx4 f = *(const floatx4*)&Wh[(long)(base_r + r)*1024 + c];
    ushort4v v;
    v[0]=f2bf(f[0]); v[1]=f2bf(f[1]); v[2]=f2bf(f[2]); v[3]=f2bf(f[3]);
    *(ushort4v*)&W_lds[r*1024 + (c ^ ((r&7)*8))] = v;
  }
  // prefill tile2[0] with own chunk of h_0 (bf16)
  {
    const int r = tid >> 4, c = (tid & 15)*4;
    floatx4 f = *(const floatx4*)&h0[(long)(bh*16 + r)*1024 + base_r + c];
    ushort4v v;
    v[0]=f2bf(f[0]); v[1]=f2bf(f[1]); v[2]=f2bf(f[2]); v[3]=f2bf(f[3]);
    *(ushort4v*)&tile2[r*72 + c] = v;
  }

  const int colf = base_r + w*16 + (lane & 15);
  const int nt_a = (base_r + w*16) >> 4;
  float hp[4];
#pragma unroll
  for (int i=0;i<4;++i){
    int gb = bh*16 + (lane>>4)*4 + i;
    hp[i] = h0[(long)gb*1024 + colf];
  }
  __syncthreads();   // W_lds + tile2[0] ready

  unsigned* myflag = flags + (bh*64 + s*4 + w)*32;   // per-wave flag
  unsigned* mflag  = flags + (bh*64 + lane)*32;      // monitor: lane L -> flag L of group
  const int hrow = lane & 15;
  const int g8   = (lane >> 4) * 8;
  const int brow = w*16 + (lane & 15);
  const int boff0 = g8 ^ ((brow & 7) * 8);
  const unsigned short* Wrow = &W_lds[brow * 1024];

  // preload alpha (atomic: keep alpha lines out of L2 forever) + wx (plain)
  long fb = (((long)0*2 + bh)*128 + nt_a)*64 + lane;
  unsigned long long a0v = __hip_atomic_load((const unsigned long long*)&frag[fb*4],
                                             __ATOMIC_RELAXED, __HIP_MEMORY_SCOPE_AGENT);
  ushort4v al = __builtin_bit_cast(ushort4v, a0v);
  ushort4v wx = *(const ushort4v*)&frag[(fb + 64*64)*4];

  for (int t=0; t<TT; ++t){
    // flag monitor: first poll issued at step top (overlaps own-chunk compute)
    bool myok = false;
    unsigned long long rdy = ~0ull;
    if (t > 0){
      unsigned v = __hip_atomic_load(mflag, __ATOMIC_RELAXED, __HIP_MEMORY_SCOPE_AGENT);
      myok = (v >= (unsigned)t);
      rdy = __ballot(myok);
    }

    const unsigned short* hsrc =
        (t == 0) ? (hinit + bh*16384) :
        (t == 1) ? (h1buf + bh*16384) :
                   (frag + ((long)(t-2)*2 + bh)*32768);

    floatx4 ac0 = (floatx4){0.f,0.f,0.f,0.f}, ac1 = ac0;

    // dj = 0: own chunk from LDS tile (kept from previous step) — no wait
    {
      const unsigned short* tcur = tile2 + (t & 1)*TILE_SZ;
      short8 a0 = *(const short8*)&tcur[hrow*72 + g8];
      short8 a1 = *(const short8*)&tcur[hrow*72 + 32 + g8];
      short8 b0 = *(const short8*)&Wrow[((s*2+0)*32) ^ boff0];
      short8 b1 = *(const short8*)&Wrow[((s*2+1)*32) ^ boff0];
      ac0 = __builtin_amdgcn_mfma_f32_16x16x32_bf16(a0, b0, ac0, 0, 0, 0);
      ac1 = __builtin_amdgcn_mfma_f32_16x16x32_bf16(a1, b1, ac1, 0, 0, 0);
    }

    // remote chunks in ring order; gate each on its producer's 4 wave-flags
#pragma unroll
    for (int dj=1; dj<16; ++dj){
      const int j = (s + dj) & 15;
      if (t > 0){
        while (((rdy >> (4*j)) & 0xFull) != 0xFull){
          if (!myok){
            unsigned v = __hip_atomic_load(mflag, __ATOMIC_RELAXED, __HIP_MEMORY_SCOPE_AGENT);
            myok = (v >= (unsigned)t);
          }
          rdy = __ballot(myok);
        }
        asm volatile("" ::: "memory");   // pin chunk loads after flag observation
      }
      const unsigned short* hp8 = &hsrc[hrow*1024 + j*64 + g8];
      short8 a0 = *(const short8*)&hp8[0];    // plain: virgin L2/L1, shared by 4 waves
      short8 a1 = *(const short8*)&hp8[32];
      short8 b0 = *(const short8*)&Wrow[((j*2+0)*32) ^ boff0];
      short8 b1 = *(const short8*)&Wrow[((j*2+1)*32) ^ boff0];
      ac0 = __builtin_amdgcn_mfma_f32_16x16x32_bf16(a0, b0, ac0, 0, 0, 0);
      ac1 = __builtin_amdgcn_mfma_f32_16x16x32_bf16(a1, b1, ac1, 0, 0, 0);
    }
    floatx4 acc = ac0 + ac1;

    // epilogue -> next tile (own chunk of h_{t+1})
    unsigned short* tnxt = tile2 + ((t+1) & 1)*TILE_SZ;
#pragma unroll
    for (int i=0;i<4;++i){
      float sv = acc[i] + bf2f(wx[i]);
      float v  = fast_tanh(sv);
      float aa = sigm(bf2f(al[i]));
      float hn = aa*hp[i] + (1.0f - aa)*v;
      tnxt[((lane>>4)*4 + i)*72 + w*16 + (lane&15)] = f2bf(hn);
      hp[i] = hn;
    }
    __syncthreads();   // tile complete (also drains vmcnt per compiler barrier semantics)

    // full-sector store: 16 consecutive tids cover 128B contiguous per row
    unsigned short* hdst = (t == 0) ? (h1buf + bh*16384)
                                    : (frag + ((long)(t-1)*2 + bh)*32768);
    {
      const int row = tid >> 4;
      const int off = (tid & 15) * 4;
      unsigned long long v = *(const unsigned long long*)&tnxt[row*72 + off];
      __hip_atomic_store((unsigned long long*)&hdst[row*1024 + base_r + off], v,
                         __ATOMIC_RELAXED, __HIP_MEMORY_SCOPE_AGENT);
    }

    if (t + 1 < TT){
      // prefetch next alpha/wx (2 outstanding loads), then wait only for the store
      fb = (((long)(t+1)*2 + bh)*128 + nt_a)*64 + lane;
      unsigned long long av = __hip_atomic_load((const unsigned long long*)&frag[fb*4],
                                                __ATOMIC_RELAXED, __HIP_MEMORY_SCOPE_AGENT);
      ushort4v wv = *(const ushort4v*)&frag[(fb + 64*64)*4];
      asm volatile("s_waitcnt vmcnt(2)" ::: "memory");  // store acked; prefetch still flying
      if (lane == 0)
        __hip_atomic_store(myflag, (unsigned)(t + 1),
                           __ATOMIC_RELAXED, __HIP_MEMORY_SCOPE_AGENT);
      al = __builtin_bit_cast(ushort4v, av);
      wx = wv;
    }
  }
}

// ---------------- expand bf16 h -> fp32 out/hout (memory-bound, off critical path)
__global__ __launch_bounds__(256) void out_writer(
    const unsigned short* __restrict__ frag,
    const unsigned short* __restrict__ h1buf,
    float* __restrict__ out, float* __restrict__ hout)
{
  const int t1 = blockIdx.z + 1;          // 1..1024
  const int bh = blockIdx.y;
  const int e  = (blockIdx.x*256 + threadIdx.x)*8;
  const int row = e >> 10, col = e & 1023;
  const unsigned short* src = (t1 == 1) ? (h1buf + bh*16384)
                                        : (frag + ((long)(t1-2)*2 + bh)*32768);
  short8 v = *(const short8*)&src[e];
  float o[8], hh[8];
#pragma unroll
  for (int j=0;j<8;++j){
    float h = bf2f((unsigned short)v[j]);
    float sg = sigm(h);
    hh[j] = h;
    o[j]  = h*h*sg;       // h * silu(h)
  }
  long ob = ((long)(t1-1)*BB + bh*16 + row)*DD + col;
  long hb = ((long)t1*BB + bh*16 + row)*DD + col;
  *(floatx4*)&out[ob]     = (floatx4){o[0],o[1],o[2],o[3]};
  *(floatx4*)&out[ob+4]   = (floatx4){o[4],o[5],o[6],o[7]};
  *(floatx4*)&hout[hb]    = (floatx4){hh[0],hh[1],hh[2],hh[3]};
  *(floatx4*)&hout[hb+4]  = (floatx4){hh[4],hh[5],hh[6],hh[7]};
}

extern "C" void kernel_launch(void* const* d_in, const int* in_sizes, int n_in,
                              void* d_out, int out_size, void* d_ws, size_t ws_size,
                              hipStream_t stream)
{
  const float* x  = (const float*)d_in[0];
  const float* h0 = (const float*)d_in[1];
  const float* Wa = (const float*)d_in[2];
  const float* ba = (const float*)d_in[3];
  const float* Wh = (const float*)d_in[4];
  const float* Wx = (const float*)d_in[5];
  const float* bx = (const float*)d_in[6];

  float* out  = (float*)d_out;                       // [T,B,D]
  float* hout = out + (long)TT*BB*DD;                // [T+1,B,D]

  uint8_t* ws = (uint8_t*)d_ws;
  unsigned short* frag  = (unsigned short*)(ws);
  unsigned short* Wcat  = (unsigned short*)(ws + WS_WCAT_OFF);
  unsigned short* hinit = (unsigned short*)(ws + WS_HINIT_OFF);
  unsigned short* h1buf = (unsigned short*)(ws + WS_H1_OFF);
  unsigned*       flags = (unsigned*)      (ws + WS_FLAG_OFF);

  init_kernel<<<8192, 256, 0, stream>>>(Wa, Wx, h0, hout, Wcat, hinit, flags);
  pre_gemm<<<dim3(16, 256), 256, 0, stream>>>(x, Wcat, ba, bx, frag);
  scan_kernel<<<32, 256, 0, stream>>>(Wh, h0, frag, hinit, h1buf, flags);
  out_writer<<<dim3(8, 2, 1024), 256, 0, stream>>>(frag, h1buf, out, hout);
}

// Round 8
// 5773.403 us; speedup vs baseline: 1.6933x; 1.1754x over previous
//
#include <hip/hip_runtime.h>
#include <hip/hip_bf16.h>
#include <stdint.h>

#define TT 1024
#define BB 32
#define DD 1024

typedef __attribute__((ext_vector_type(8))) short short8;
typedef __attribute__((ext_vector_type(4))) unsigned short ushort4v;
typedef __attribute__((ext_vector_type(4))) float floatx4;

static __device__ __forceinline__ unsigned short f2bf(float f){
  unsigned u = __float_as_uint(f);
  u += 0x7fffu + ((u >> 16) & 1u);   // RNE
  return (unsigned short)(u >> 16);
}
static __device__ __forceinline__ float bf2f(unsigned short s){
  return __uint_as_float(((unsigned)s) << 16);
}
static __device__ __forceinline__ float sigm(float x){
  return __fdividef(1.0f, 1.0f + __expf(-x));
}
static __device__ __forceinline__ float fast_tanh(float x){
  float e = __expf(2.0f * x);
  return 1.0f - __fdividef(2.0f, e + 1.0f);
}

// ---------------- workspace layout (bytes) ----------------
// frag: [t][bh(2)][nt(128)][lane(64)][4] bf16; nt 0..63 alpha preact, 64..127 wx.
// Timeline for frag[v]'s alpha half (32KB per (v,bh)):
//   step v-1: ATOMIC (sc1, L2-bypass) alpha prefetch read   -> no L1/L2 copy ever
//   step v+1: ATOMIC full-sector h stores (h_{v+2})         -> lands in MALL
//   step v+2: PLAIN h loads                                 -> L2 miss -> fresh MALL
// (pre_gemm's writes are flushed from L2s at its kernel-end release.)
#define WS_FRAG_BYTES (134217728ull)                 // 1024*2*128*64*4*2
#define WS_WCAT_OFF   (WS_FRAG_BYTES)
#define WS_WCAT_BYTES (4194304ull)                   // 2048*1024*2 bf16 [Walpha;Wx]
#define WS_HINIT_OFF  (WS_WCAT_OFF + WS_WCAT_BYTES)  // 32*1024 bf16 h0
#define WS_H1_OFF     (WS_HINIT_OFF + 65536ull)      // 32*1024 bf16 h1
#define WS_CNT_OFF    (WS_H1_OFF + 65536ull)         // 2 counters, 128B apart

// ---------------- init
__global__ void init_kernel(const float* __restrict__ Wa, const float* __restrict__ Wx,
                            const float* __restrict__ h0, float* __restrict__ hout0,
                            unsigned short* __restrict__ Wcat,
                            unsigned short* __restrict__ hinit,
                            unsigned* __restrict__ cnt)
{
  long i = (long)blockIdx.x * 256 + threadIdx.x;
  if (blockIdx.x == 0 && threadIdx.x < 2)
    __hip_atomic_store(&cnt[threadIdx.x * 32], 0u, __ATOMIC_RELAXED, __HIP_MEMORY_SCOPE_AGENT);
  const long NW = 2048L * 1024L;
  for (long idx = i; idx < NW; idx += (long)gridDim.x * 256L){
    long r = idx >> 10, c = idx & 1023;
    float v = (r < 1024) ? Wa[r*1024 + c] : Wx[(r-1024)*1024 + c];
    Wcat[idx] = f2bf(v);
  }
  const long NH = 32L * 1024L;
  for (long idx = i; idx < NH; idx += (long)gridDim.x * 256L){
    float v = h0[idx];
    hinit[idx] = f2bf(v);
    hout0[idx] = v;          // hout[0] = h0 (fp32)
  }
}

// ---------------- precompute GEMM (unchanged)
__global__ __launch_bounds__(256) void pre_gemm(
    const float* __restrict__ x, const unsigned short* __restrict__ Wcat,
    const float* __restrict__ b_alpha, const float* __restrict__ b_x,
    unsigned short* __restrict__ frag)
{
  __shared__ unsigned short A_lds[128*72];
  __shared__ unsigned short B_lds[128*72];
  const int tid = threadIdx.x;
  const int lane = tid & 63;
  const int w = tid >> 6;
  const int wm = w >> 1, wn = w & 1;
  const long m0 = (long)blockIdx.y * 128;
  const int n0 = blockIdx.x * 128;

  floatx4 acc[4][4];
#pragma unroll
  for (int i=0;i<4;++i)
#pragma unroll
    for (int j=0;j<4;++j) acc[i][j] = (floatx4){0.f,0.f,0.f,0.f};

  for (int kt=0; kt<16; ++kt){
    const int k0 = kt*64;
    __syncthreads();
#pragma unroll
    for (int rep=0; rep<4; ++rep){
      int flat = rep*2048 + tid*8;
      int r = flat >> 6, c = flat & 63;
      const float* src = &x[(m0 + r)*1024 + k0 + c];
      floatx4 f0 = *(const floatx4*)src;
      floatx4 f1 = *(const floatx4*)(src + 4);
      short8 v;
      v[0]=(short)f2bf(f0[0]); v[1]=(short)f2bf(f0[1]); v[2]=(short)f2bf(f0[2]); v[3]=(short)f2bf(f0[3]);
      v[4]=(short)f2bf(f1[0]); v[5]=(short)f2bf(f1[1]); v[6]=(short)f2bf(f1[2]); v[7]=(short)f2bf(f1[3]);
      *(short8*)&A_lds[r*72 + c] = v;
      short8 bv = *(const short8*)&Wcat[(long)(n0 + r)*1024 + k0 + c];
      *(short8*)&B_lds[r*72 + c] = bv;
    }
    __syncthreads();
#pragma unroll
    for (int kb=0; kb<2; ++kb){
      short8 a[4], b[4];
#pragma unroll
      for (int f=0; f<4; ++f)
        a[f] = *(const short8*)&A_lds[(wm*64 + f*16 + (lane&15))*72 + kb*32 + (lane>>4)*8];
#pragma unroll
      for (int f=0; f<4; ++f)
        b[f] = *(const short8*)&B_lds[(wn*64 + f*16 + (lane&15))*72 + kb*32 + (lane>>4)*8];
#pragma unroll
      for (int fm=0; fm<4; ++fm)
#pragma unroll
        for (int fn=0; fn<4; ++fn)
          acc[fm][fn] = __builtin_amdgcn_mfma_f32_16x16x32_bf16(a[fm], b[fn], acc[fm][fn], 0, 0, 0);
    }
  }

#pragma unroll
  for (int fm=0; fm<4; ++fm){
    const long mrow = m0 + wm*64 + fm*16;
    const int t  = (int)(mrow >> 5);
    const int bh = (int)((mrow >> 4) & 1);
#pragma unroll
    for (int fn=0; fn<4; ++fn){
      const int nf  = n0 + wn*64 + fn*16;
      const int nt  = nf >> 4;
      const int col = nf + (lane & 15);
      floatx4 v = acc[fm][fn];
      const float bias = (col < DD) ? b_alpha[col] : b_x[col - DD];
      ushort4v o;
#pragma unroll
      for (int i=0;i<4;++i) o[i] = f2bf(v[i] + bias);
      *(ushort4v*)&frag[((((long)t*2 + bh)*128 + nt)*64 + lane)*4] = o;
    }
  }
}

// ---------------- sequential scan (32 wgs = 2 groups x 16 slices)
// Fence-free. Cross-wg h: full-sector relaxed-atomic stores (MALL) -> plain loads
// into virgin L1/L2 lines (see frag comment). Barrier: one monotonic relaxed
// counter per group; producers bump after vmcnt(0)+barrier (stores globally
// visible at MALL first); tid0 polls, __syncthreads releases the wg.
__global__ __launch_bounds__(256, 1) void scan_kernel(
    const float* __restrict__ Wh, const float* __restrict__ h0,
    unsigned short* frag,
    const unsigned short* __restrict__ hinit,
    unsigned short* h1buf,
    unsigned* cnt)
{
  __shared__ unsigned short W_lds[64*1024];  // XOR-swizzled, 128 KB
  __shared__ unsigned short tile[16*72];     // per-step h staging
  const int tid  = threadIdx.x;
  const int lane = tid & 63;
  const int w    = tid >> 6;
  const int bh   = blockIdx.x & 1;
  const int s    = blockIdx.x >> 1;     // 0..15 weight slice
  const int base_r = s * 64;

  // W_h slice fp32 -> bf16 LDS, 16B-granule XOR swizzle: (r,c) at r*1024 + (c ^ ((r&7)*8))
  for (int it=0; it<64; ++it){
    const int r = it, c = tid*4;
    floatx4 f = *(const floatx4*)&Wh[(long)(base_r + r)*1024 + c];
    ushort4v v;
    v[0]=f2bf(f[0]); v[1]=f2bf(f[1]); v[2]=f2bf(f[2]); v[3]=f2bf(f[3]);
    *(ushort4v*)&W_lds[r*1024 + (c ^ ((r&7)*8))] = v;
  }

  const int colf = base_r + w*16 + (lane & 15);
  const int nt_a = (base_r + w*16) >> 4;
  float hp[4];
#pragma unroll
  for (int i=0;i<4;++i){
    int gb = bh*16 + (lane>>4)*4 + i;
    hp[i] = h0[(long)gb*1024 + colf];
  }
  __syncthreads();

  unsigned* mycnt = cnt + bh*32;
  const int hrow = lane & 15;
  const int g8   = (lane >> 4) * 8;
  const int brow = w*16 + (lane & 15);
  const int boff0 = g8 ^ ((brow & 7) * 8);
  const unsigned short* Wrow = &W_lds[brow * 1024];

  // preload alpha (atomic: keeps alpha lines out of L1/L2 forever) + wx (plain)
  long fb = (((long)0*2 + bh)*128 + nt_a)*64 + lane;
  unsigned long long a0v = __hip_atomic_load((const unsigned long long*)&frag[fb*4],
                                             __ATOMIC_RELAXED, __HIP_MEMORY_SCOPE_AGENT);
  ushort4v al = __builtin_bit_cast(ushort4v, a0v);
  ushort4v wx = *(const ushort4v*)&frag[(fb + 64*64)*4];

  for (int t=0; t<TT; ++t){
    if (t > 0){
      if (tid == 0){
        const unsigned tgt = (unsigned)t * 16u;
        while (__hip_atomic_load(mycnt, __ATOMIC_RELAXED, __HIP_MEMORY_SCOPE_AGENT) < tgt) { }
      }
      __syncthreads();                  // release all waves after count reached
      asm volatile("" ::: "memory");    // pin h loads below the poll
    }

    const unsigned short* hsrc =
        (t == 0) ? (hinit + bh*16384) :
        (t == 1) ? (h1buf + bh*16384) :
                   (frag + ((long)(t-2)*2 + bh)*32768);

    floatx4 ac0 = (floatx4){0.f,0.f,0.f,0.f}, ac1 = ac0, ac2 = ac0, ac3 = ac0;
#pragma unroll
    for (int kb=0; kb<32; kb+=4){
#pragma unroll
      for (int j=0;j<4;++j){
        short8 afr = *(const short8*)&hsrc[hrow*1024 + (kb+j)*32 + g8];  // plain: virgin L2
        short8 bfr = *(const short8*)&Wrow[((kb+j)*32) ^ boff0];
        if (j==0) ac0 = __builtin_amdgcn_mfma_f32_16x16x32_bf16(afr, bfr, ac0, 0, 0, 0);
        if (j==1) ac1 = __builtin_amdgcn_mfma_f32_16x16x32_bf16(afr, bfr, ac1, 0, 0, 0);
        if (j==2) ac2 = __builtin_amdgcn_mfma_f32_16x16x32_bf16(afr, bfr, ac2, 0, 0, 0);
        if (j==3) ac3 = __builtin_amdgcn_mfma_f32_16x16x32_bf16(afr, bfr, ac3, 0, 0, 0);
      }
    }
    floatx4 acc = (ac0 + ac1) + (ac2 + ac3);

    // prefetch next step's alpha (atomic) / wx (plain) NOW: latency hides under
    // epilogue + stores; vmcnt(0) below waits max(store,prefetch), not sum.
    unsigned long long av = 0; ushort4v wv = wx;
    if (t + 1 < TT){
      fb = (((long)(t+1)*2 + bh)*128 + nt_a)*64 + lane;
      av = __hip_atomic_load((const unsigned long long*)&frag[fb*4],
                             __ATOMIC_RELAXED, __HIP_MEMORY_SCOPE_AGENT);
      wv = *(const ushort4v*)&frag[(fb + 64*64)*4];
    }

    // epilogue -> LDS tile (rows=batch-in-group, cols=wg-local feature)
#pragma unroll
    for (int i=0;i<4;++i){
      float sv = acc[i] + bf2f(wx[i]);
      float v  = fast_tanh(sv);
      float aa = sigm(bf2f(al[i]));
      float hn = aa*hp[i] + (1.0f - aa)*v;
      tile[((lane>>4)*4 + i)*72 + w*16 + (lane&15)] = f2bf(hn);
      hp[i] = hn;
    }
    __syncthreads();   // tile complete

    // full-sector store: 16 consecutive tids cover 128B contiguous per row
    unsigned short* hdst = (t == 0) ? (h1buf + bh*16384)
                                    : (frag + ((long)(t-1)*2 + bh)*32768);
    {
      const int row = tid >> 4;
      const int off = (tid & 15) * 4;
      unsigned long long v = *(const unsigned long long*)&tile[row*72 + off];
      __hip_atomic_store((unsigned long long*)&hdst[row*1024 + base_r + off], v,
                         __ATOMIC_RELAXED, __HIP_MEMORY_SCOPE_AGENT);
    }

    if (t + 1 < TT){
      asm volatile("s_waitcnt vmcnt(0)" ::: "memory");  // h stores visible at MALL
      __syncthreads();                                  // all 4 waves drained
      if (tid == 0)
        __hip_atomic_fetch_add(mycnt, 1u, __ATOMIC_RELAXED, __HIP_MEMORY_SCOPE_AGENT);
      al = __builtin_bit_cast(ushort4v, av);
      wx = wv;
    }
  }
}

// ---------------- expand bf16 h -> fp32 out/hout (memory-bound, off critical path)
__global__ __launch_bounds__(256) void out_writer(
    const unsigned short* __restrict__ frag,
    const unsigned short* __restrict__ h1buf,
    float* __restrict__ out, float* __restrict__ hout)
{
  const int t1 = blockIdx.z + 1;          // 1..1024
  const int bh = blockIdx.y;
  const int e  = (blockIdx.x*256 + threadIdx.x)*8;
  const int row = e >> 10, col = e & 1023;
  const unsigned short* src = (t1 == 1) ? (h1buf + bh*16384)
                                        : (frag + ((long)(t1-2)*2 + bh)*32768);
  short8 v = *(const short8*)&src[e];
  float o[8], hh[8];
#pragma unroll
  for (int j=0;j<8;++j){
    float h = bf2f((unsigned short)v[j]);
    float sg = sigm(h);
    hh[j] = h;
    o[j]  = h*h*sg;       // h * silu(h)
  }
  long ob = ((long)(t1-1)*BB + bh*16 + row)*DD + col;
  long hb = ((long)t1*BB + bh*16 + row)*DD + col;
  *(floatx4*)&out[ob]     = (floatx4){o[0],o[1],o[2],o[3]};
  *(floatx4*)&out[ob+4]   = (floatx4){o[4],o[5],o[6],o[7]};
  *(floatx4*)&hout[hb]    = (floatx4){hh[0],hh[1],hh[2],hh[3]};
  *(floatx4*)&hout[hb+4]  = (floatx4){hh[4],hh[5],hh[6],hh[7]};
}

extern "C" void kernel_launch(void* const* d_in, const int* in_sizes, int n_in,
                              void* d_out, int out_size, void* d_ws, size_t ws_size,
                              hipStream_t stream)
{
  const float* x  = (const float*)d_in[0];
  const float* h0 = (const float*)d_in[1];
  const float* Wa = (const float*)d_in[2];
  const float* ba = (const float*)d_in[3];
  const float* Wh = (const float*)d_in[4];
  const float* Wx = (const float*)d_in[5];
  const float* bx = (const float*)d_in[6];

  float* out  = (float*)d_out;                       // [T,B,D]
  float* hout = out + (long)TT*BB*DD;                // [T+1,B,D]

  uint8_t* ws = (uint8_t*)d_ws;
  unsigned short* frag  = (unsigned short*)(ws);
  unsigned short* Wcat  = (unsigned short*)(ws + WS_WCAT_OFF);
  unsigned short* hinit = (unsigned short*)(ws + WS_HINIT_OFF);
  unsigned short* h1buf = (unsigned short*)(ws + WS_H1_OFF);
  unsigned*       cnt   = (unsigned*)      (ws + WS_CNT_OFF);

  init_kernel<<<8192, 256, 0, stream>>>(Wa, Wx, h0, hout, Wcat, hinit, cnt);
  pre_gemm<<<dim3(16, 256), 256, 0, stream>>>(x, Wcat, ba, bx, frag);
  scan_kernel<<<32, 256, 0, stream>>>(Wh, h0, frag, hinit, h1buf, cnt);
  out_writer<<<dim3(8, 2, 1024), 256, 0, stream>>>(frag, h1buf, out, hout);
}